// Round 4
// baseline (484.453 us; speedup 1.0000x reference)
//
#include <hip/hip_runtime.h>

#define N_FEAT 50
#define HID 16
#define NC 10
#define TPB 256

#define NPB 512          // nodes per bucket (power of 2)
#define NPB_SHIFT 9
#define CAP 10240        // edge capacity per bucket (mean 8192, +22 sigma)
#define BIN_VPT 32
#define BIN_CHUNK (TPB * BIN_VPT)   // 8192 edges per block
#define APB 512          // threads per agg block
#define ACCP 17          // padded row stride for LDS accumulators

// ---------------- init: bucket cursors ----------------

__global__ void init_kernel(int* __restrict__ bcur) {
    int t = threadIdx.x;                 // one block of 256
    bcur[t] = t * CAP;
}

// ---------------- binning: edges -> bucket-contiguous packed words ----------------
// word = (src << 9) | (dst & 511); bucket = dst >> 9

__global__ void bin_kernel(const int* __restrict__ src, const int* __restrict__ dst, int E,
                           int* __restrict__ bcur, int* __restrict__ ebuf) {
    __shared__ int hist[256];
    __shared__ int base[256];
    int t = threadIdx.x;
    hist[t] = 0;
    __syncthreads();

    int blockBase = blockIdx.x * BIN_CHUNK;
#pragma unroll
    for (int i = 0; i < BIN_VPT; i++) {
        int e = blockBase + i * TPB + t;
        if (e < E) {
            int d = dst[e];
            atomicAdd(&hist[d >> NPB_SHIFT], 1);
        }
    }
    __syncthreads();
    int c = hist[t];
    base[t] = atomicAdd(&bcur[t], c);
    hist[t] = 0;
    __syncthreads();
#pragma unroll
    for (int i = 0; i < BIN_VPT; i++) {
        int e = blockBase + i * TPB + t;
        if (e < E) {
            int d = dst[e];
            int s = src[e];
            int b = d >> NPB_SHIFT;
            int off = atomicAdd(&hist[b], 1);
            int idx = base[b] + off;
            if (idx < (b + 1) * CAP)     // overflow guard (never expected)
                ebuf[idx] = (s << NPB_SHIFT) | (d & (NPB - 1));
        }
    }
}

// ---------------- per-bucket degree -> dinv ----------------

__global__ __launch_bounds__(APB)
void deg_kernel(const int* __restrict__ bcur, const int* __restrict__ ebuf,
                int n, float* __restrict__ dinv) {
    __shared__ int hist[NPB];
    int t = threadIdx.x;
    int b = blockIdx.x;
    int bBase = b * CAP;
    int count = bcur[b] - bBase;
    if (count > CAP) count = CAP;
    hist[t] = 0;
    __syncthreads();
    for (int k = t; k < count; k += APB)
        atomicAdd(&hist[ebuf[bBase + k] & (NPB - 1)], 1);
    __syncthreads();
    int node = b * NPB + t;
    if (node < n) {
        int d = hist[t];
        dinv[node] = (d > 0) ? rsqrtf((float)d) : 0.0f;
    }
}

// ---------------- layer-1 node matmuls ----------------
// s1 = x @ w1_0 ; t1s = dinv[node] * (x @ w1_1)   (both stride 16)

__global__ void node1_kernel(const float* __restrict__ x,
                             const float* __restrict__ w10,
                             const float* __restrict__ w11,
                             const float* __restrict__ dinv,
                             int n,
                             float* __restrict__ s1,
                             float* __restrict__ t1s) {
    __shared__ float sw0[N_FEAT * HID];
    __shared__ float sw1[N_FEAT * HID];
    __shared__ float sx[TPB * (N_FEAT + 1)];
    for (int i = threadIdx.x; i < N_FEAT * HID; i += TPB) {
        sw0[i] = w10[i];
        sw1[i] = w11[i];
    }
    int base = blockIdx.x * TPB;
    int cnt = n - base; if (cnt > TPB) cnt = TPB;
    for (int idx = threadIdx.x; idx < cnt * N_FEAT; idx += TPB) {
        int ln = idx / N_FEAT;
        int c  = idx - ln * N_FEAT;
        sx[ln * (N_FEAT + 1) + c] = x[(size_t)base * N_FEAT + idx];
    }
    __syncthreads();
    int local = threadIdx.x;
    int node = base + local;
    if (node >= n) return;

    float xr[N_FEAT];
#pragma unroll
    for (int i = 0; i < N_FEAT; i++) xr[i] = sx[local * (N_FEAT + 1) + i];

    float di = dinv[node];
    float* s1p = s1 + (size_t)node * HID;
    float* tp  = t1s + (size_t)node * HID;
#pragma unroll
    for (int j = 0; j < HID; j++) {
        float a0 = 0.f, a1 = 0.f;
#pragma unroll
        for (int i = 0; i < N_FEAT; i++) {
            a0 += xr[i] * sw0[i * HID + j];
            a1 += xr[i] * sw1[i * HID + j];
        }
        s1p[j] = a0;
        tp[j]  = di * a1;
    }
}

// ---------------- agg layer 1 + node2 fused ----------------
// per bucket: LDS-accumulate t1s over incoming edges; epilogue computes
// h = relu(s1 + di*acc + b1) and writes s2p16 = h@w2_0, ps16 = di*(h@w2_1)

__global__ __launch_bounds__(APB)
void agg1_kernel(const int* __restrict__ bcur, const int* __restrict__ ebuf,
                 const float4* __restrict__ t1s4,
                 const float4* __restrict__ s1v4,
                 const float* __restrict__ dinv,
                 const float* __restrict__ b1,
                 const float* __restrict__ w20,
                 const float* __restrict__ w21,
                 int n,
                 float* __restrict__ s2p16,
                 float* __restrict__ ps16) {
    __shared__ float acc[NPB * ACCP];
    __shared__ float sw0[HID * NC];
    __shared__ float sw1[HID * NC];
    __shared__ float sb1[HID];
    int t = threadIdx.x;
    int b = blockIdx.x;
    int bBase = b * CAP;
    int count = bcur[b] - bBase;
    if (count > CAP) count = CAP;

    for (int i = t; i < NPB * ACCP; i += APB) acc[i] = 0.f;
    if (t < HID * NC) { sw0[t] = w20[t]; sw1[t] = w21[t]; }
    if (t < HID) sb1[t] = b1[t];
    __syncthreads();

    int q = t & 3;           // float4 quarter
    int g = t >> 2;          // edge group 0..127
    int k = g;
    for (; k + 128 < count; k += 256) {
        int w0 = ebuf[bBase + k];
        int w1 = ebuf[bBase + k + 128];
        float4 v0 = t1s4[(size_t)(w0 >> NPB_SHIFT) * 4 + q];
        float4 v1 = t1s4[(size_t)(w1 >> NPB_SHIFT) * 4 + q];
        int d0 = (w0 & (NPB - 1)) * ACCP + q * 4;
        int d1 = (w1 & (NPB - 1)) * ACCP + q * 4;
        atomicAdd(&acc[d0 + 0], v0.x); atomicAdd(&acc[d0 + 1], v0.y);
        atomicAdd(&acc[d0 + 2], v0.z); atomicAdd(&acc[d0 + 3], v0.w);
        atomicAdd(&acc[d1 + 0], v1.x); atomicAdd(&acc[d1 + 1], v1.y);
        atomicAdd(&acc[d1 + 2], v1.z); atomicAdd(&acc[d1 + 3], v1.w);
    }
    for (; k < count; k += 128) {
        int w = ebuf[bBase + k];
        float4 v = t1s4[(size_t)(w >> NPB_SHIFT) * 4 + q];
        int d = (w & (NPB - 1)) * ACCP + q * 4;
        atomicAdd(&acc[d + 0], v.x); atomicAdd(&acc[d + 1], v.y);
        atomicAdd(&acc[d + 2], v.z); atomicAdd(&acc[d + 3], v.w);
    }
    __syncthreads();

    int node = b * NPB + t;
    if (node >= n) return;
    float di = dinv[node];
    float4 sv0 = s1v4[(size_t)node * 4 + 0];
    float4 sv1 = s1v4[(size_t)node * 4 + 1];
    float4 sv2 = s1v4[(size_t)node * 4 + 2];
    float4 sv3 = s1v4[(size_t)node * 4 + 3];
    float h[HID];
    const float* ar = &acc[t * ACCP];
    h[0]  = fmaxf(sv0.x + di * ar[0]  + sb1[0],  0.f);
    h[1]  = fmaxf(sv0.y + di * ar[1]  + sb1[1],  0.f);
    h[2]  = fmaxf(sv0.z + di * ar[2]  + sb1[2],  0.f);
    h[3]  = fmaxf(sv0.w + di * ar[3]  + sb1[3],  0.f);
    h[4]  = fmaxf(sv1.x + di * ar[4]  + sb1[4],  0.f);
    h[5]  = fmaxf(sv1.y + di * ar[5]  + sb1[5],  0.f);
    h[6]  = fmaxf(sv1.z + di * ar[6]  + sb1[6],  0.f);
    h[7]  = fmaxf(sv1.w + di * ar[7]  + sb1[7],  0.f);
    h[8]  = fmaxf(sv2.x + di * ar[8]  + sb1[8],  0.f);
    h[9]  = fmaxf(sv2.y + di * ar[9]  + sb1[9],  0.f);
    h[10] = fmaxf(sv2.z + di * ar[10] + sb1[10], 0.f);
    h[11] = fmaxf(sv2.w + di * ar[11] + sb1[11], 0.f);
    h[12] = fmaxf(sv3.x + di * ar[12] + sb1[12], 0.f);
    h[13] = fmaxf(sv3.y + di * ar[13] + sb1[13], 0.f);
    h[14] = fmaxf(sv3.z + di * ar[14] + sb1[14], 0.f);
    h[15] = fmaxf(sv3.w + di * ar[15] + sb1[15], 0.f);

    float so[16], po[16];
#pragma unroll
    for (int c = 0; c < NC; c++) {
        float a0 = 0.f, a1 = 0.f;
#pragma unroll
        for (int j = 0; j < HID; j++) {
            a0 += h[j] * sw0[j * NC + c];
            a1 += h[j] * sw1[j * NC + c];
        }
        so[c] = a0;
        po[c] = di * a1;
    }
#pragma unroll
    for (int c = NC; c < 16; c++) { so[c] = 0.f; po[c] = 0.f; }

    float4* s2v = (float4*)(s2p16 + (size_t)node * 16);
    float4* psv = (float4*)(ps16 + (size_t)node * 16);
#pragma unroll
    for (int i = 0; i < 4; i++) {
        s2v[i] = make_float4(so[4 * i], so[4 * i + 1], so[4 * i + 2], so[4 * i + 3]);
        psv[i] = make_float4(po[4 * i], po[4 * i + 1], po[4 * i + 2], po[4 * i + 3]);
    }
}

// ---------------- agg layer 2 + log_softmax fused ----------------

__global__ __launch_bounds__(APB)
void agg2_kernel(const int* __restrict__ bcur, const int* __restrict__ ebuf,
                 const float4* __restrict__ ps4,
                 const float4* __restrict__ s2v4,
                 const float* __restrict__ dinv,
                 const float* __restrict__ b2,
                 int n,
                 float* __restrict__ out) {
    __shared__ float acc[NPB * ACCP];
    __shared__ float sb2[NC];
    int t = threadIdx.x;
    int b = blockIdx.x;
    int bBase = b * CAP;
    int count = bcur[b] - bBase;
    if (count > CAP) count = CAP;

    for (int i = t; i < NPB * ACCP; i += APB) acc[i] = 0.f;
    if (t < NC) sb2[t] = b2[t];
    __syncthreads();

    int q = t & 3;
    int g = t >> 2;
    int k = g;
    for (; k + 128 < count; k += 256) {
        int w0 = ebuf[bBase + k];
        int w1 = ebuf[bBase + k + 128];
        float4 v0 = ps4[(size_t)(w0 >> NPB_SHIFT) * 4 + q];
        float4 v1 = ps4[(size_t)(w1 >> NPB_SHIFT) * 4 + q];
        int d0 = (w0 & (NPB - 1)) * ACCP + q * 4;
        int d1 = (w1 & (NPB - 1)) * ACCP + q * 4;
        atomicAdd(&acc[d0 + 0], v0.x); atomicAdd(&acc[d0 + 1], v0.y);
        atomicAdd(&acc[d0 + 2], v0.z); atomicAdd(&acc[d0 + 3], v0.w);
        atomicAdd(&acc[d1 + 0], v1.x); atomicAdd(&acc[d1 + 1], v1.y);
        atomicAdd(&acc[d1 + 2], v1.z); atomicAdd(&acc[d1 + 3], v1.w);
    }
    for (; k < count; k += 128) {
        int w = ebuf[bBase + k];
        float4 v = ps4[(size_t)(w >> NPB_SHIFT) * 4 + q];
        int d = (w & (NPB - 1)) * ACCP + q * 4;
        atomicAdd(&acc[d + 0], v.x); atomicAdd(&acc[d + 1], v.y);
        atomicAdd(&acc[d + 2], v.z); atomicAdd(&acc[d + 3], v.w);
    }
    __syncthreads();

    int node = b * NPB + t;
    if (node >= n) return;
    float di = dinv[node];
    float4 a0 = s2v4[(size_t)node * 4 + 0];
    float4 a1 = s2v4[(size_t)node * 4 + 1];
    float4 a2 = s2v4[(size_t)node * 4 + 2];
    float sf[12] = {a0.x, a0.y, a0.z, a0.w, a1.x, a1.y, a1.z, a1.w,
                    a2.x, a2.y, a2.z, a2.w};
    const float* ar = &acc[t * ACCP];
    float v[NC];
    float mx = -1e30f;
#pragma unroll
    for (int c = 0; c < NC; c++) {
        v[c] = sf[c] + di * ar[c] + sb2[c];
        mx = fmaxf(mx, v[c]);
    }
    float se = 0.f;
#pragma unroll
    for (int c = 0; c < NC; c++) se += expf(v[c] - mx);
    float ls = logf(se);
    float2* op = (float2*)(out + (size_t)node * NC);
#pragma unroll
    for (int i = 0; i < 5; i++)
        op[i] = make_float2(v[2 * i] - mx - ls, v[2 * i + 1] - mx - ls);
}

// ---------------- launch ----------------

extern "C" void kernel_launch(void* const* d_in, const int* in_sizes, int n_in,
                              void* d_out, int out_size, void* d_ws, size_t ws_size,
                              hipStream_t stream) {
    const float* x    = (const float*)d_in[0];
    const int*   ei   = (const int*)d_in[1];
    const float* w10  = (const float*)d_in[2];
    const float* w11  = (const float*)d_in[3];
    const float* b1   = (const float*)d_in[4];
    const float* w20  = (const float*)d_in[5];
    const float* w21  = (const float*)d_in[6];
    const float* b2   = (const float*)d_in[7];
    float* out = (float*)d_out;

    int n = in_sizes[0] / N_FEAT;   // 100000
    int E = in_sizes[1] / 2;        // 1600000
    const int* src = ei;
    const int* dst = ei + E;

    int NB = (n + NPB - 1) >> NPB_SHIFT;   // 196

    auto align256 = [](size_t v) { return (v + 255) & ~(size_t)255; };

    size_t off = 0;
    int*   bcur  = (int*)((char*)d_ws + off);   off = align256(off + 256 * 4);
    int*   ebuf  = (int*)((char*)d_ws + off);   off = align256(off + (size_t)NB * CAP * 4);
    float* dinv  = (float*)((char*)d_ws + off); off = align256(off + (size_t)n * 4);
    float* s1    = (float*)((char*)d_ws + off); off = align256(off + (size_t)n * HID * 4);
    float* t1s   = (float*)((char*)d_ws + off); off = align256(off + (size_t)n * HID * 4);
    float* s2p16 = (float*)((char*)d_ws + off); off = align256(off + (size_t)n * 16 * 4);
    float* ps16  = (float*)((char*)d_ws + off); off = align256(off + (size_t)n * 16 * 4);

    const int B = TPB;
    init_kernel<<<1, 256, 0, stream>>>(bcur);
    bin_kernel<<<(E + BIN_CHUNK - 1) / BIN_CHUNK, B, 0, stream>>>(src, dst, E, bcur, ebuf);
    deg_kernel<<<NB, APB, 0, stream>>>(bcur, ebuf, n, dinv);
    node1_kernel<<<(n + B - 1) / B, B, 0, stream>>>(x, w10, w11, dinv, n, s1, t1s);
    agg1_kernel<<<NB, APB, 0, stream>>>(bcur, ebuf, (const float4*)t1s, (const float4*)s1,
                                        dinv, b1, w20, w21, n, s2p16, ps16);
    agg2_kernel<<<NB, APB, 0, stream>>>(bcur, ebuf, (const float4*)ps16, (const float4*)s2p16,
                                        dinv, b2, n, out);
}